// Round 1
// baseline (239.912 us; speedup 1.0000x reference)
//
#include <hip/hip_runtime.h>

// Fused attention, masked-key compaction, 6 dispatches.
// R9: replace all three GEMM dispatches (qkvt, S, PV) with an 8-phase
// counted-vmcnt pipeline (T3+T4) + setprio (T5), plain-HIP port of the
// verified 8-phase template. Tile 128x256, BK=64, 512 thr / 8 waves,
// wave-tile 64x64, 96KB LDS double-buffer, raw s_barrier (no syncthreads
// -> no vmcnt(0) drain in the K-loop). Staging keeps the proven
// global_load_lds + XOR-swizzle scheme (0 bank conflicts, R2).
// Schedule (per iter = 2 K-tiles t,t+1; bufs 0/1):
//   P0 rdA01,B01(buf0) | stgB0(t1->buf1) | bar lgk0 mfma bar
//   P1 rdB23           | stgB1(t1)       | ...
//   P2 rdA23           | -               | ...
//   P3 -               | stgA(t2->buf0)  | bar mfma vmcnt(2) bar
//   P4..P7 mirror on buf1, stgB(t2), stgA(t3->buf1), vmcnt(2)
// B01 frags kept in regs so each buffer's last ds_read is >=1 phase
// before its restage (barrier+lgkmcnt(0) separate them). Last iter:
// no prefetch, vmcnt(0) at P3.
// N over npad uses ceil-256 tiles; poison rows beyond npad never reach
// the output (softmax selects by counts; PV reads k<npad only).
// R8 lesson retained: VGPR budget matters -> 128-row tiles (acc 64 regs).
//  L1 prep / L2 gather / L5 softmax unchanged.

typedef _Float16 f16;
typedef _Float16 f16x4 __attribute__((ext_vector_type(4)));
typedef _Float16 f16x8 __attribute__((ext_vector_type(8)));
typedef float f32x4 __attribute__((ext_vector_type(4)));

#define LB256 __launch_bounds__(256)

__device__ __forceinline__ void gld16(const void* gp, void* lp) {
  __builtin_amdgcn_global_load_lds(
      (__attribute__((address_space(1))) void*)(gp),
      (__attribute__((address_space(3))) void*)(lp),
      16, 0, 0);
}

#define BAR() __builtin_amdgcn_s_barrier()
#define SCB() __builtin_amdgcn_sched_barrier(0)
#define LGK0()                                         \
  do {                                                 \
    asm volatile("s_waitcnt lgkmcnt(0)" ::: "memory"); \
    __builtin_amdgcn_sched_barrier(0);                 \
  } while (0)
#define VMW(N)                                            \
  do {                                                    \
    asm volatile("s_waitcnt vmcnt(" #N ")" ::: "memory"); \
    __builtin_amdgcn_sched_barrier(0);                    \
  } while (0)

// ds_read of a 2x2 fragment group (compile-time indices only, rule #20)
#define RD_A(DST, DB, IB)                                                     \
  _Pragma("unroll") for (int ii = 0; ii < 2; ++ii) _Pragma("unroll")          \
      for (int ss = 0; ss < 2; ++ss) DST[ii][ss] =                            \
          *(const f16x8*)&lds[(DB)*24576 + (wm + ((IB) + ii) * 16 + lo) * 64  \
                              + swz + (ss ? 32 - ks0 : ks0)]
#define RD_B(DST, DB, JB)                                                     \
  _Pragma("unroll") for (int jj = 0; jj < 2; ++jj) _Pragma("unroll")          \
      for (int ss = 0; ss < 2; ++ss) DST[jj][ss] =                            \
          *(const f16x8*)&lds[(DB)*24576 + 8192 +                             \
                              (wn + ((JB) + jj) * 16 + lo) * 64 + swz +       \
                              (ss ? 32 - ks0 : ks0)]

// one C-quadrant x K=64: 8 MFMA, setprio-wrapped (T5)
#define MFMA_Q(AF, BF, AI, BJ)                                                \
  do {                                                                        \
    __builtin_amdgcn_s_setprio(1);                                            \
    _Pragma("unroll") for (int ii = 0; ii < 2; ++ii) _Pragma("unroll")        \
        for (int jj = 0; jj < 2; ++jj) _Pragma("unroll")                      \
            for (int ss = 0; ss < 2; ++ss)                                    \
                acc[(AI) + ii][(BJ) + jj] =                                   \
                    __builtin_amdgcn_mfma_f32_16x16x32_f16(                   \
                        AF[ii][ss], BF[jj][ss], acc[(AI) + ii][(BJ) + jj],    \
                        0, 0, 0);                                             \
    __builtin_amdgcn_s_setprio(0);                                            \
  } while (0)

// ------------------------------------------------ 128x256 8-phase GEMM body
// C[m0..m0+127][n0..n0+255] = A[128xK] * B[256xK]^T  (both row-major, ld in f16)
// BIAS: 0 = +bias[col], 1 = +bias[row], 2 = none. K mult of 128, K>=128.
template <typename OutT, int BIAS>
__device__ __forceinline__ void gemm8p(
    f16* lds, const f16* __restrict__ A, int lda, const f16* __restrict__ B,
    int ldb, OutT* __restrict__ C, int ldc, const float* __restrict__ bias,
    float scale, int K, int m0, int n0) {
  const int tid = (int)threadIdx.x;
  const int w = tid >> 6, l = tid & 63;
  const int wm = (w >> 2) * 64;  // 0,64
  const int wn = (w & 3) * 64;   // 0,64,128,192
  const int quad = l >> 4, lo = l & 15;
  const int rl = l >> 3;
  const int scol = ((l & 7) ^ rl) * 8;
  const int swz = (quad ^ (lo & 3)) * 8;
  const int ks0 = ((lo >> 2) & 1) * 32;

  f32x4 acc[4][4] = {};
  f16x8 a01[2][2], a23[2][2], b01[2][2], b23[2][2];

  // LDS (f16 offsets): buf d at d*24576: A 128x64 (8192) then B 256x64 (16384)
  auto stgA = [&](int db, int kk2) {
#pragma unroll
    for (int q = 0; q < 2; ++q) {
      const int c8 = q * 8 + w;  // 16 blocks of 8 rows
      gld16(A + (long)(m0 + c8 * 8 + rl) * lda + kk2 + scol,
            &lds[db * 24576 + c8 * 512]);
    }
  };
  auto stgB = [&](int db, int half, int kk2) {
#pragma unroll
    for (int q = 0; q < 2; ++q) {
      const int c8 = half * 16 + q * 8 + w;  // 32 blocks of 8 rows
      gld16(B + (long)(n0 + c8 * 8 + rl) * ldb + kk2 + scol,
            &lds[db * 24576 + 8192 + c8 * 512]);
    }
  };

  // prologue: tile0 full -> buf0, A-chunk of tile1 -> buf1
  stgA(0, 0);
  stgB(0, 0, 0);
  stgB(0, 1, 0);
  stgA(1, 64);
  VMW(2);
  BAR();

  const int NH = K >> 7;  // 2 K-tiles per iteration
  int kk = 0;
#pragma unroll 1
  for (int it = 0; it < NH; ++it) {
    const bool lastit = (it == NH - 1);
    const int k1 = kk + 64, k2 = kk + 128, k3 = kk + 192;
    // ---- P0 (tile t, buf0)
    RD_A(a01, 0, 0);
    RD_B(b01, 0, 0);
    stgB(1, 0, k1);
    BAR();
    LGK0();
    MFMA_Q(a01, b01, 0, 0);
    SCB();
    BAR();
    // ---- P1
    RD_B(b23, 0, 2);
    stgB(1, 1, k1);
    BAR();
    LGK0();
    MFMA_Q(a01, b23, 0, 2);
    SCB();
    BAR();
    // ---- P2 (last buf0 reads)
    RD_A(a23, 0, 2);
    BAR();
    LGK0();
    MFMA_Q(a23, b23, 2, 2);
    SCB();
    BAR();
    // ---- P3 (regs only; buf0 free -> prefetch t+2 A)
    if (!lastit) stgA(0, k2);
    BAR();
    MFMA_Q(a23, b01, 2, 0);
    SCB();
    if (!lastit) {
      VMW(2);
    } else {
      VMW(0);
    }
    BAR();
    // ---- P4 (tile t+1, buf1)
    RD_A(a01, 1, 0);
    RD_B(b01, 1, 0);
    if (!lastit) stgB(0, 0, k2);
    BAR();
    LGK0();
    MFMA_Q(a01, b01, 0, 0);
    SCB();
    BAR();
    // ---- P5
    RD_B(b23, 1, 2);
    if (!lastit) stgB(0, 1, k2);
    BAR();
    LGK0();
    MFMA_Q(a01, b23, 0, 2);
    SCB();
    BAR();
    // ---- P6 (last buf1 reads)
    RD_A(a23, 1, 2);
    BAR();
    LGK0();
    MFMA_Q(a23, b23, 2, 2);
    SCB();
    BAR();
    // ---- P7 (regs only; buf1 free -> prefetch t+3 A)
    if (!lastit) stgA(1, k3);
    BAR();
    MFMA_Q(a23, b01, 2, 0);
    SCB();
    if (!lastit) {
      VMW(2);
      BAR();
    }
    kk += 128;
  }

  // epilogue: C/D layout col=lane&15, row=quad*4+reg
#pragma unroll
  for (int i = 0; i < 4; ++i) {
    const int rowb = m0 + wm + i * 16 + quad * 4;
#pragma unroll
    for (int j = 0; j < 4; ++j) {
      const int col = n0 + wn + j * 16 + lo;
      float bc;
      if (BIAS == 0)
        bc = bias[col];
      else
        bc = 0.f;
#pragma unroll
      for (int r = 0; r < 4; ++r) {
        const float bb = (BIAS == 1) ? bias[rowb + r] : bc;
        C[(long)(rowb + r) * ldc + col] = (OutT)(acc[i][j][r] * scale + bb);
      }
    }
  }
}

// ---------------------------------------------------------------- L1 prep
__global__ LB256 void prep(const float* __restrict__ x, const float* __restrict__ wq,
                           const float* __restrict__ wk, const float* __restrict__ wv,
                           const void* __restrict__ maskp, f16* __restrict__ xh,
                           f16* __restrict__ wh, int* __restrict__ sel,
                           int* __restrict__ counts, int* __restrict__ npad) {
  const int blk = blockIdx.x;
  const int t = threadIdx.x;
  if (blk < 11264) {
    long i = ((long)blk * 256 + t) * 4;
    const float* src;
    f16* dst;
    if (i < 8388608L) {
      src = x + i;
      dst = xh + i;
    } else {
      long j = i - 8388608L;
      int which = (int)(j >> 20);
      const float* ws = which == 0 ? wq : (which == 1 ? wk : wv);
      src = ws + (j & 1048575L);
      dst = wh + j;
    }
    float4 v = *(const float4*)src;
    f16x4 o;
    o[0] = (f16)v.x; o[1] = (f16)v.y; o[2] = (f16)v.z; o[3] = (f16)v.w;
    *(f16x4*)dst = o;
  } else {
    const int b = blk - 11264;
    __shared__ int bad;
    __shared__ int s[256];
    if (t == 0) bad = 0;
    __syncthreads();
    const int* mi = (const int*)maskp;
    int loc = 0;
    for (int i = t; i < 2048; i += 256)
      if ((unsigned)mi[i] > 1u) loc = 1;  // byte-packed bools look like big ints
    if (loc) atomicOr(&bad, 1);
    __syncthreads();
    const bool bytemode = bad != 0;
    int m[8];
    if (bytemode) {
      const unsigned char* p = (const unsigned char*)maskp + b * 2048 + t * 8;
#pragma unroll
      for (int e = 0; e < 8; ++e) m[e] = p[e] != 0;
    } else {
      const int* p = mi + b * 2048 + t * 8;
#pragma unroll
      for (int e = 0; e < 8; ++e) m[e] = p[e] != 0;
    }
    int local = 0;
#pragma unroll
    for (int e = 0; e < 8; ++e) local += m[e];
    s[t] = local;
    __syncthreads();
    for (int off = 1; off < 256; off <<= 1) {
      int v = (t >= off) ? s[t - off] : 0;
      __syncthreads();
      s[t] += v;
      __syncthreads();
    }
    int offp = s[t] - local;
#pragma unroll
    for (int e = 0; e < 8; ++e)
      if (m[e]) sel[b * 2048 + offp++] = t * 8 + e;
    if (t == 0) {
      counts[b] = s[255];
      npad[b] = ((s[255] + 127) >> 7) << 7;
    }
  }
}

// ---------------------------------------------------------------- L2 gather
__global__ LB256 void gather_x(const f16* __restrict__ xh, const int* __restrict__ sel,
                               const int* __restrict__ counts,
                               const int* __restrict__ npad, f16* __restrict__ xc) {
  const int b = blockIdx.y;
  const int np = npad[b], cnt = counts[b];
  const int t = threadIdx.x;
#pragma unroll
  for (int i = 0; i < 4; ++i) {
    const int sp = blockIdx.x * 4 + i;
    if (sp >= np) continue;
    f16* dst = xc + ((long)b * 2048 + sp) * 1024;
    if (sp >= cnt) {
      *(f16x4*)(dst + t * 4) = (f16x4){0, 0, 0, 0};
    } else {
      const f16* src = xh + ((long)b * 2048 + sel[b * 2048 + sp]) * 1024;
      *(f16x4*)(dst + t * 4) = *(const f16x4*)(src + t * 4);
    }
  }
}

// ---------------------------------------------------------------- L3 Q+K+Vt
// Q: 64m x 4n, id=n*64+m (same-m ids = m mod 8 -> same XCD L2).
// K: per-batch m-tiles npad/128 (exact), id=256+n*MK+r (MK mult 8).
// Vt: 8m x ceil(npad/256) n; reads of xc rows >=npad are poison but those
// Vt cols are never read by PV (k<npad).
__global__ __launch_bounds__(512, 2) void qkvt8p(
    const f16* __restrict__ xh, const f16* __restrict__ xc,
    const f16* __restrict__ Wh, f16* __restrict__ Qb, f16* __restrict__ Kc,
    f16* __restrict__ Vt, const float* __restrict__ bq,
    const float* __restrict__ bk, const float* __restrict__ bv,
    const int* __restrict__ npad) {
  __shared__ __align__(16) f16 lds[49152];
  int cum[5], cv[5];
  cum[0] = cv[0] = 0;
#pragma unroll
  for (int b = 0; b < 4; ++b) {
    const int np = npad[b];
    cum[b + 1] = cum[b] + (np >> 7);
    cv[b + 1] = cv[b] + ((np + 255) >> 8);
  }
  const int rowsK = cum[4], rowsV = cv[4];
  const int MK = (rowsK + 7) & ~7;
  const int MV = (rowsV + 7) & ~7;
  const int TK = 4 * MK, TV = 8 * MV;
  const int T = 256 + TK + TV;
  for (int t = blockIdx.x; t < T; t += gridDim.x) {
    if (t < 256) {
      const int m = t & 63, n = t >> 6;
      gemm8p<f16, 0>(lds, xh, 1024, Wh, 1024, Qb, 1024, bq, 1.f, 1024,
                     m * 128, n * 256);
    } else if (t < 256 + TK) {
      const int u = t - 256;
      const int n = u / MK, r = u % MK;
      if (r >= rowsK) continue;
      int b = 0;
      while (r >= cum[b + 1]) ++b;
      const int m = r - cum[b];
      gemm8p<f16, 0>(lds, xc + (long)b * 2097152, 1024, Wh + 1048576, 1024,
                     Kc + (long)b * 2097152, 1024, bk, 1.f, 1024, m * 128,
                     n * 256);
    } else {
      const int u = t - 256 - TK;
      const int m = u / MV, r = u % MV;
      if (r >= rowsV) continue;
      int b = 0;
      while (r >= cv[b + 1]) ++b;
      const int n = r - cv[b];
      gemm8p<f16, 1>(lds, Wh + 2097152, 1024, xc + (long)b * 2097152, 1024,
                     Vt + (long)b * 2097152, 2048, bv, 1.f, 1024, m * 128,
                     n * 256);
    }
  }
}

// ---------------------------------------------------------------- L4 S GEMM
// 16m x ceil(npad/256) n per batch; Kc rows >=npad are poison -> S cols
// >=npad garbage, but softmax only reads values at idx<counts and PV only
// reads k<npad.
__global__ __launch_bounds__(512, 2) void s8p(const f16* __restrict__ Qb,
                                              const f16* __restrict__ Kc,
                                              f16* __restrict__ Sbuf,
                                              const int* __restrict__ npad) {
  __shared__ __align__(16) f16 lds[49152];
  int cv[5];
  cv[0] = 0;
#pragma unroll
  for (int b = 0; b < 4; ++b) cv[b + 1] = cv[b] + ((npad[b] + 255) >> 8);
  const int rowsN = cv[4];
  const int Np = (rowsN + 7) & ~7;
  const int T = 16 * Np;
  for (int t = blockIdx.x; t < T; t += gridDim.x) {
    const int m = t / Np, rn = t % Np;
    if (rn >= rowsN) continue;
    int b = 0;
    while (rn >= cv[b + 1]) ++b;
    const int n = rn - cv[b];
    gemm8p<f16, 2>(lds, Qb + (long)b * 2097152, 1024, Kc + (long)b * 2097152,
                   1024, Sbuf + (long)b * 4194304, 2048, nullptr, 0.03125f,
                   1024, m * 128, n * 256);
  }
}

// ---------------------------------------------------------------- L5 softmax
__global__ LB256 void softmax_w(f16* __restrict__ S, const int* __restrict__ counts,
                                const int* __restrict__ npad) {
  const int wv = threadIdx.x >> 6, l = threadIdx.x & 63;
  const long r = (long)blockIdx.x * 4 + wv;
  const int b = (int)(r >> 11);
  const int nv = counts[b], np = npad[b];
  f16* row = S + r * 2048;

  float v[4][8];
  bool have[4];
  float mx = -3.0e38f;
#pragma unroll
  for (int g = 0; g < 4; ++g) {
    const int idx = (g * 64 + l) * 8;
    have[g] = idx < np;
    if (have[g]) {
      f16x8 sv = *(const f16x8*)(row + idx);
#pragma unroll
      for (int e = 0; e < 8; ++e) {
        float s = (idx + e < nv) ? (float)sv[e] : -3.0e38f;
        v[g][e] = s;
        mx = fmaxf(mx, s);
      }
    } else {
#pragma unroll
      for (int e = 0; e < 8; ++e) v[g][e] = -3.0e38f;
    }
  }
#pragma unroll
  for (int off = 32; off > 0; off >>= 1) mx = fmaxf(mx, __shfl_xor(mx, off, 64));

  float sum = 0.f;
  float ev[4][8];
#pragma unroll
  for (int g = 0; g < 4; ++g)
#pragma unroll
    for (int e = 0; e < 8; ++e) {
      float t = (v[g][e] <= -1.0e38f) ? 0.f : __expf(v[g][e] - mx);
      ev[g][e] = t;
      sum += t;
    }
#pragma unroll
  for (int off = 32; off > 0; off >>= 1) sum += __shfl_xor(sum, off, 64);
  const float inv = 1.f / sum;
#pragma unroll
  for (int g = 0; g < 4; ++g) {
    if (!have[g]) continue;
    const int idx = (g * 64 + l) * 8;
    f16x8 ov;
#pragma unroll
    for (int e = 0; e < 8; ++e) ov[e] = (f16)(ev[g][e] * inv);
    *(f16x8*)(row + idx) = ov;
  }
}

// ---------------------------------------------------------------- L6 PV GEMM
// O = P @ Vt^T, K=npad[b]. 16m x 4n per batch -> exactly 256 tiles, 1/CU.
// id = n*64 + (b*16+m): same Sbuf panel ids congruent mod 8 -> same XCD.
__global__ __launch_bounds__(512, 2) void pv8p(const f16* __restrict__ Sbuf,
                                               const f16* __restrict__ Vt,
                                               float* __restrict__ out,
                                               const int* __restrict__ npad) {
  __shared__ __align__(16) f16 lds[49152];
  for (int t = blockIdx.x; t < 256; t += gridDim.x) {
    const int n = t >> 6, u = t & 63, b = u >> 4, m = u & 15;
    const int K = npad[b];
    if (K < 128) continue;
    gemm8p<float, 2>(lds, Sbuf + (long)b * 4194304, 2048,
                     Vt + (long)b * 2097152, 2048, out + (long)b * 2097152,
                     1024, nullptr, 1.f, K, m * 128, n * 256);
  }
}

// ---------------------------------------------------------------- launch
extern "C" void kernel_launch(void* const* d_in, const int* in_sizes, int n_in,
                              void* d_out, int out_size, void* d_ws, size_t ws_size,
                              hipStream_t stream) {
  const float* x = (const float*)d_in[0];
  const void* mask = d_in[1];
  const float* Wq = (const float*)d_in[2];
  const float* bq = (const float*)d_in[3];
  const float* Wk = (const float*)d_in[4];
  const float* bk = (const float*)d_in[5];
  const float* Wv = (const float*)d_in[6];
  const float* bv = (const float*)d_in[7];
  float* out = (float*)d_out;

  // Workspace (f16 elems), 118 MB total (proven available in R1).
  f16* xh = (f16*)d_ws;              // 8M  [0,16MB)
  f16* xc = xh + 8388608;            // 8M  [16,32)
  f16* Wh = xc + 8388608;            // 3M  [32,38)  [Wq|Wk|Wv]
  f16* Qb = Wh + 3145728;            // 8M  [38,54)
  f16* Kc = Qb + 8388608;            // 8M  [54,70)
  f16* Vt = Kc + 8388608;            // 8M  [70,86)
  f16* Sbuf = Vt + 8388608;          // 16M [86,118)
  int* sel = (int*)(Sbuf + 16777216);
  int* counts = sel + 8192;
  int* npad = counts + 4;

  prep<<<11268, 256, 0, stream>>>(x, Wq, Wk, Wv, mask, xh, Wh, sel, counts, npad);
  gather_x<<<dim3(512, 4), 256, 0, stream>>>(xh, sel, counts, npad, xc);
  qkvt8p<<<256, 512, 0, stream>>>(xh, xc, Wh, Qb, Kc, Vt, bq, bk, bv, npad);
  s8p<<<256, 512, 0, stream>>>(Qb, Kc, Sbuf, npad);
  softmax_w<<<2048, 256, 0, stream>>>(Sbuf, counts, npad);
  pv8p<<<256, 512, 0, stream>>>(Sbuf, Vt, out, npad);
}